// Round 8
// baseline (55.563 us; speedup 1.0000x reference)
//
#include <hip/hip_runtime.h>

typedef __attribute__((ext_vector_type(8))) __bf16 bf16x8;
typedef __attribute__((ext_vector_type(4))) float f32x4;

#define M_ 256
#define N_ 4096
#define K_ 4096
#define SPLITK 4
#define KC 1024            // K_/SPLITK
#define BN 64
#define BK 32
#define KSTEPS 32          // KC/BK
#define BUFSZ 36864        // per-buffer LDS: A 32KB (hi 16 + lo 16 tiles) + B 4KB (4 tiles)
#define GIOFF 73728        // Ginv copy after the two buffers

// Tiled operand layout (xgh/xgl, produced by k_xg): 1KB tile = 16 rows x 32 k,
// tile(rt,kt) at ushort offset (rt*128+kt)*512; within: lane=(row&15)+16*(kgrp), elem=k&7.
// global_load_lds reads each tile as one contiguous 1KB (lane*16B), zero scatter.

// ---------- helpers ----------

__device__ __forceinline__ unsigned short f2bf(float f) {
  unsigned int u = __builtin_bit_cast(unsigned int, f);
  u += 0x7fffu + ((u >> 16) & 1u);
  return (unsigned short)(u >> 16);
}

__device__ __forceinline__ void async16(const void* g, void* l) {
  __builtin_amdgcn_global_load_lds(
      (const __attribute__((address_space(1))) unsigned int*)g,
      (__attribute__((address_space(3))) unsigned int*)l, 16, 0, 0);
}

__device__ __forceinline__ float lsq1(float y, float a, float s) {
  float yc = fminf(fmaxf(y, -a), a);
  return rintf(yc / s) * s;
}

// z lattice-quantize 8 elems -> packed bf16 bits. EXACT verified chain:
// f32 UNFUSED mul+add, sequential ascending j — bit-matches XLA:CPU ref.
// DO NOT TOUCH (absmax 0.0117 verified in rounds 3-7).
__device__ __forceinline__ uint4 zpack(float4 wA, float4 wB, float sc,
                                       const float* __restrict__ Gi) {
  const float wsv[8] = {wA.x * sc, wA.y * sc, wA.z * sc, wA.w * sc,
                        wB.x * sc, wB.y * sc, wB.z * sc, wB.w * sc};
  unsigned int packed[4] = {0u, 0u, 0u, 0u};
  const unsigned long long lut = 0x3F800000BF80C000ull;  // idx 0..3 -> -2,-1,0,+1 (bf16)
#pragma unroll
  for (int i = 0; i < 8; ++i) {
    float t = 0.f;
#pragma unroll
    for (int j = 0; j < 8; ++j)
      t = __fadd_rn(t, __fmul_rn(wsv[j], Gi[j * 8 + i]));  // unfused, sequential
    const int zi = (int)rintf(t);
    const int idx = (zi + 2) & 3;
    const unsigned int h = (unsigned int)((lut >> (idx * 16)) & 0xFFFFull);
    packed[i >> 1] |= h << ((i & 1) * 16);
  }
  return make_uint4(packed[0], packed[1], packed[2], packed[3]);
}

// ---------- K1: xg = x_blocks @ G^T -> bf16 hi/lo (tiled layout) ----------

__global__ __launch_bounds__(256) void k_xg(const float* __restrict__ x,
                                            const float* __restrict__ G,
                                            unsigned short* __restrict__ hi,
                                            unsigned short* __restrict__ lo) {
  __shared__ float Gs[64];
  const int tid = threadIdx.x;
  if (tid < 64) Gs[tid] = G[tid];
  __syncthreads();
  const int s = blockIdx.x * 256 + tid;       // output 16B slot
  const int lane6 = s & 63;
  const int tile = s >> 6;
  const int m  = ((tile >> 7) << 4) + (lane6 & 15);
  const int kb = ((tile & 127) << 2) + (lane6 >> 4);
  const float4* xp = (const float4*)(x + ((size_t)m << 12) + ((size_t)kb << 3));
  const float4 a0 = xp[0], a1 = xp[1];
  float xv[8] = {a0.x, a0.y, a0.z, a0.w, a1.x, a1.y, a1.z, a1.w};
  unsigned int ph[4] = {0u, 0u, 0u, 0u}, pl[4] = {0u, 0u, 0u, 0u};
#pragma unroll
  for (int i = 0; i < 8; ++i) {
    float t = 0.f;
#pragma unroll
    for (int j = 0; j < 8; ++j) t = fmaf(xv[j], Gs[i * 8 + j], t);
    const unsigned short hb = f2bf(t);
    const float hf = __builtin_bit_cast(float, (unsigned int)hb << 16);
    const unsigned short lb = f2bf(t - hf);
    ph[i >> 1] |= ((unsigned int)hb) << ((i & 1) * 16);
    pl[i >> 1] |= ((unsigned int)lb) << ((i & 1) * 16);
  }
  *(uint4*)(hi + ((size_t)s << 3)) = make_uint4(ph[0], ph[1], ph[2], ph[3]);
  *(uint4*)(lo + ((size_t)s << 3)) = make_uint4(pl[0], pl[1], pl[2], pl[3]);
}

// ---------- K2: fused quantize+GEMM ----------
// grid 256 = (sk 4) x (nt 64); block = 512 thr = 8 waves; BM=256 (all M), BN=64.
// Waves 0-3 (z-role): per step compute the B-tile z from W in-register (wave w
//   <-> B fragment tile w; lane computes its own 8 z) and ds_write_b128 it.
//   W loads for step ks+1 issue at step ks top -> latency under MFMA.
// Waves 4-7 (stage-role): 8 global_load_lds each -> next A buffer; per-wave
//   counted wait (their own 8 loads only). NO global vmcnt(0) drain anywhere.
// One raw s_barrier per step (lgkmcnt(0) before it). Double buffer: step ks
// writes buffer (ks+1)&1, whose previous reads retired before barrier ks-1.
// Per-accumulator MFMA order (ascending k32, hi-then-lo) identical to the
// verified rounds -> partials bit-identical.

__global__ __launch_bounds__(512, 2) void k_gemm(const float* __restrict__ W,
                                                 const float* __restrict__ theta,
                                                 const float* __restrict__ Ginv,
                                                 const unsigned short* __restrict__ xgh,
                                                 const unsigned short* __restrict__ xgl,
                                                 float* __restrict__ part,
                                                 int kTheta) {
  __shared__ uint4 smem4[(2 * BUFSZ + 256) / 16];
  char* smem = (char*)smem4;
  float* Gi = (float*)(smem + GIOFF);

  const int tid = threadIdx.x;
  const int lane = tid & 63, wave = tid >> 6;
  const int wr = wave >> 1, wc = wave & 1;   // MFMA wave grid 4m x 2n (64x32 each)
  const int b = blockIdx.x;
  const int sk = b & 3, nt = b >> 2;
  const int lrow = lane & 15, lkg = lane >> 4;

  if (tid < 64) Gi[tid] = Ginv[tid];

  const bool zrole = (wave < 4);

  // stage-role setup (waves 4-7): 8 chunks each; c 0..15 = A_hi tile c&15, 16..31 = A_lo
  const unsigned short* asrc[8];
  int aldo[8];
  if (!zrole) {
    const int wv = wave - 4;
#pragma unroll
    for (int i = 0; i < 8; ++i) {
      const int c = wv * 8 + i;
      const int rt = c & 15;
      const unsigned short* P = (c < 16) ? xgh : xgl;
      asrc[i] = P + (((size_t)(rt * 128 + sk * 32)) << 9) + lane * 8;
      aldo[i] = ((c < 16) ? 0 : 16384) + rt * 1024;
    }
  }

  // z-role setup (waves 0-3): lane owns B row zr, k-group lkg
  int zr = 0;
  float sc = 0.f;
  const float* wbase = nullptr;
  if (zrole) {
    zr = nt * 64 + wave * 16 + lrow;
    for (int t = 0; t < kTheta; ++t) sc += theta[zr * kTheta + t];
    sc /= (float)kTheta;
    wbase = W + ((size_t)zr << 12) + ((size_t)(sk * 128 + lkg) << 3);
  }

  f32x4 acc[4][2] = {};

  // ---- prologue ----
  float4 wA, wB;
  if (zrole) {
    wA = *(const float4*)(wbase + 0);   // W(step 0)
    wB = *(const float4*)(wbase + 4);
  } else {
#pragma unroll
    for (int i = 0; i < 8; ++i) async16(asrc[i], smem + aldo[i]);  // A(0) -> buf0
  }
  asm volatile("s_waitcnt lgkmcnt(0)" ::: "memory");
  __builtin_amdgcn_s_barrier();                       // Gi visible to all waves
  if (zrole) {
    *(uint4*)(smem + 32768 + wave * 1024 + lane * 16) = zpack(wA, wB, sc, Gi);  // B(0)
    wA = *(const float4*)(wbase + 32);  // W(step 1)
    wB = *(const float4*)(wbase + 36);
  } else {
    asm volatile("s_waitcnt vmcnt(0)" ::: "memory");  // A(0) landed (per-wave)
  }
  asm volatile("s_waitcnt lgkmcnt(0)" ::: "memory");
  __builtin_amdgcn_s_barrier();                       // buf0 fully ready

  // ---- main loop: one barrier per step ----
  for (int ks = 0; ks < KSTEPS; ++ks) {
    const int curo = (ks & 1) * BUFSZ;
    const int nxto = BUFSZ - curo;

    if (!zrole && ks + 1 < KSTEPS) {
#pragma unroll
      for (int i = 0; i < 8; ++i)
        async16(asrc[i] + (((size_t)(ks + 1)) << 9), smem + nxto + aldo[i]);
    }

    bf16x8 ah[4], al[4], bfr[2];
#pragma unroll
    for (int mf = 0; mf < 4; ++mf) {
      ah[mf] = *(const bf16x8*)(smem + curo + (wr * 4 + mf) * 1024 + lane * 16);
      al[mf] = *(const bf16x8*)(smem + curo + 16384 + (wr * 4 + mf) * 1024 + lane * 16);
    }
#pragma unroll
    for (int nf = 0; nf < 2; ++nf)
      bfr[nf] = *(const bf16x8*)(smem + curo + 32768 + (wc * 2 + nf) * 1024 + lane * 16);

#pragma unroll
    for (int mf = 0; mf < 4; ++mf)
#pragma unroll
      for (int nf = 0; nf < 2; ++nf) {
        acc[mf][nf] = __builtin_amdgcn_mfma_f32_16x16x32_bf16(ah[mf], bfr[nf], acc[mf][nf], 0, 0, 0);
        acc[mf][nf] = __builtin_amdgcn_mfma_f32_16x16x32_bf16(al[mf], bfr[nf], acc[mf][nf], 0, 0, 0);
      }

    if (zrole) {
      if (ks + 1 < KSTEPS) {
        *(uint4*)(smem + nxto + 32768 + wave * 1024 + lane * 16) = zpack(wA, wB, sc, Gi);
        if (ks + 2 < KSTEPS) {
          wA = *(const float4*)(wbase + (size_t)(ks + 2) * 32);
          wB = *(const float4*)(wbase + (size_t)(ks + 2) * 32 + 4);
        }
      }
    } else {
      asm volatile("s_waitcnt vmcnt(0)" ::: "memory");  // A(ks+1) landed (per-wave, 8 loads)
    }
    asm volatile("s_waitcnt lgkmcnt(0)" ::: "memory");
    __builtin_amdgcn_s_barrier();
  }

  // C/D layout (m89-verified): col = lane&15, row = (lane>>4)*4 + reg
  float* pb = part + (size_t)sk * (M_ * N_);
#pragma unroll
  for (int mf = 0; mf < 4; ++mf)
#pragma unroll
    for (int nf = 0; nf < 2; ++nf)
#pragma unroll
      for (int r = 0; r < 4; ++r) {
        const int m = wr * 64 + mf * 16 + lkg * 4 + r;
        const int n = nt * 64 + wc * 32 + nf * 16 + lrow;
        pb[(size_t)m * N_ + n] = acc[mf][nf][r];
      }
}

// ---------- K3: reduce split-K partials + bias + LSQ epilogue ----------

__global__ __launch_bounds__(256) void k_epi(const float* __restrict__ part,
                                             const float* __restrict__ bias,
                                             const float* __restrict__ alpha,
                                             float* __restrict__ out) {
  const int i4 = blockIdx.x * 256 + threadIdx.x;  // over M_*N_/4
  const size_t off = (size_t)i4 * 4;
  const float4 p0 = *(const float4*)(part + off);
  const float4 p1 = *(const float4*)(part + (size_t)1 * M_ * N_ + off);
  const float4 p2 = *(const float4*)(part + (size_t)2 * M_ * N_ + off);
  const float4 p3 = *(const float4*)(part + (size_t)3 * M_ * N_ + off);
  const int n = (int)(off & (N_ - 1));
  const float4 bv = *(const float4*)(bias + n);
  const float a = fmaxf(alpha[0], 0.f) + 1e-8f;
  const float s = a / 127.0f;
  float4 o;
  o.x = lsq1(((p0.x + p1.x) + p2.x) + p3.x + bv.x, a, s);
  o.y = lsq1(((p0.y + p1.y) + p2.y) + p3.y + bv.y, a, s);
  o.z = lsq1(((p0.z + p1.z) + p2.z) + p3.z + bv.z, a, s);
  o.w = lsq1(((p0.w + p1.w) + p2.w) + p3.w + bv.w, a, s);
  *(float4*)(out + off) = o;
}

// ---------- launch ----------

extern "C" void kernel_launch(void* const* d_in, const int* in_sizes, int n_in,
                              void* d_out, int out_size, void* d_ws, size_t ws_size,
                              hipStream_t stream) {
  const float* x     = (const float*)d_in[0];
  const float* W     = (const float*)d_in[1];
  const float* bias  = (const float*)d_in[2];
  const float* theta = (const float*)d_in[3];
  const float* alpha = (const float*)d_in[4];
  const float* G     = (const float*)d_in[5];
  const float* Ginv  = (const float*)d_in[6];
  float* out = (float*)d_out;

  const int O = in_sizes[2];           // 4096
  const int kTheta = in_sizes[3] / O;  // 1

  // ws layout: xg_hi 2MB | xg_lo 2MB | partials [S][M][N] 16MB
  char* ws = (char*)d_ws;
  unsigned short* xgh = (unsigned short*)ws;
  unsigned short* xgl = (unsigned short*)(ws + 2097152);
  float* part = (float*)(ws + 4194304);
  if (ws_size < 20971520) return;  // guard: need 20MB scratch

  k_xg<<<(M_ * K_ / 8) / 256, 256, 0, stream>>>(x, G, xgh, xgl);
  k_gemm<<<SPLITK * (N_ / BN), 512, 0, stream>>>(W, theta, Ginv, xgh, xgl, part, kTheta);
  k_epi<<<(M_ * N_ / 4) / 256, 256, 0, stream>>>(part, bias, alpha, out);
}